// Round 22
// baseline (537.586 us; speedup 1.0000x reference)
//
#include <hip/hip_runtime.h>

typedef unsigned short u16;
typedef __attribute__((ext_vector_type(8))) __bf16 bf16x8;
typedef __attribute__((ext_vector_type(4))) __bf16 bf16x4;
typedef __attribute__((ext_vector_type(4))) float f32x4;

#define DEV __device__ __forceinline__

// ---------- helpers ----------
DEV u16 f2bf(float f) {                       // RNE float -> bf16 bits
  unsigned u = __builtin_bit_cast(unsigned, f);
  u += 0x7FFFu + ((u >> 16) & 1u);
  return (u16)(u >> 16);
}
DEV float bf2f(u16 u) {
  unsigned v = (unsigned)u << 16;
  return __builtin_bit_cast(float, v);
}

DEV void stage16(const void* g, void* l) {    // async global->LDS, 16B/lane
  __builtin_amdgcn_global_load_lds((const __attribute__((address_space(1))) void*)g,
                                   (__attribute__((address_space(3))) void*)l, 16, 0, 0);
}

DEV f32x4 mfma32(bf16x8 a, bf16x8 b, f32x4 c) {
  return __builtin_amdgcn_mfma_f32_16x16x32_bf16(a, b, c, 0, 0, 0);
}

// ---------- fused prep: weight transposes + W1 cast + input cast ----------
DEV void transpose_tile(const float* __restrict__ src, u16* __restrict__ dst,
                        int R, int C, int bx, int by, int t, float (*tile)[33]) {
  int tx = t & 31, ty = t >> 5;
  int c0 = bx * 32, r0 = by * 32;
#pragma unroll
  for (int i = 0; i < 4; ++i)
    tile[ty + i * 8][tx] = src[(size_t)(r0 + ty + i * 8) * C + c0 + tx];
  __syncthreads();
#pragma unroll
  for (int i = 0; i < 4; ++i)
    dst[(size_t)(c0 + ty + i * 8) * R + r0 + tx] = f2bf(tile[tx][ty + i * 8]);
}

__global__ __launch_bounds__(256) void prep_all(
    const float* __restrict__ Wq, const float* __restrict__ Wk, const float* __restrict__ Wv,
    const float* __restrict__ W1, const float* __restrict__ W2,
    const float* __restrict__ inputs,
    u16* __restrict__ WqkvT, u16* __restrict__ W1b, u16* __restrict__ W2T,
    u16* __restrict__ Xb) {
  __shared__ float tile[32][33];
  const int t = threadIdx.x;
  const int bid = blockIdx.x;
  if (bid < 1728) {                    // Wq/Wk/Wv: 3 x (24 x 24) tiles of 768x768
    int z = bid / 576, rem = bid % 576;
    const float* src = (z == 0) ? Wq : (z == 1 ? Wk : Wv);
    transpose_tile(src, WqkvT + (size_t)z * 768 * 768, 768, 768, rem % 24, rem / 24, t, tile);
  } else if (bid < 4032) {             // W2 [3072][768] -> W2T [768][3072]
    int rem = bid - 1728;
    transpose_tile(W2, W2T, 3072, 768, rem % 24, rem / 24, t, tile);
  } else if (bid < 6336) {             // cast W1 f32 -> bf16 row-major, 2304 blocks
    int i = (bid - 4032) * 256 + t;
    float4 f = ((const float4*)W1)[i];
    ushort4 u;
    u.x = f2bf(f.x); u.y = f2bf(f.y); u.z = f2bf(f.z); u.w = f2bf(f.w);
    ((ushort4*)W1b)[i] = u;
  } else {                             // cast inputs f32 -> bf16, 6144 blocks
    int i = (bid - 6336) * 256 + t;
    float4 f = ((const float4*)inputs)[i];
    ushort4 u;
    u.x = f2bf(f.x); u.y = f2bf(f.y); u.z = f2bf(f.z); u.w = f2bf(f.w);
    ((ushort4*)Xb)[i] = u;
  }
}

// ---------- bf16 GEMM body: C[M,N] = A[M,K] @ Bt[N,K]^T, 128x128 tile, BK=32 ----------
// MODE 0: QKV epilogue (scatter Q*scale,K to [bh,s,dh]; V to [bh,dh,s])
// MODE 2: split-K/2 by bz: z=0 raw partial bf16 -> outQ; z=1 partial+bias+resid bf16 -> outK
// MODE 4: split-K/4 by bz: f32 transposed partial -> outP (W12 = W1 @ W2)
template <int MODE>
DEV void gemm_body(u16 (*Als)[128 * 32], u16 (*Bls)[128 * 32],
                   const u16* __restrict__ A, const u16* __restrict__ Bt, int K,
                   const float* __restrict__ b0, const float* __restrict__ b1p,
                   const float* __restrict__ b2p, const u16* __restrict__ resid,
                   u16* __restrict__ outQ, u16* __restrict__ outK, u16* __restrict__ outV,
                   float* __restrict__ outP, int bx, int by, int bz) {
  const int t = threadIdx.x;
  const int lane = t & 63, wv = t >> 6;
  const int wm = wv & 1, wn = wv >> 1;
  const int lrow = lane & 15, g = lane >> 4;
  const int m0 = by * 128, n0 = bx * 128;

  int koff = 0, klen = K;
  if (MODE == 2) { klen = K >> 1; koff = bz * klen; }
  if (MODE == 4) { klen = K >> 2; koff = bz * klen; }

  f32x4 acc[4][4] = {};

  const int idx0 = t, idx1 = 256 + t;
  const int row0 = idx0 >> 2, sl0 = (idx0 & 3) ^ ((row0 >> 1) & 3);
  const int row1 = idx1 >> 2, sl1 = (idx1 & 3) ^ ((row1 >> 1) & 3);

  auto stage = [&](int k0, int buf) {
    stage16(A + (size_t)(m0 + row0) * K + koff + k0 + sl0 * 8, (char*)Als[buf] + idx0 * 16);
    stage16(Bt + (size_t)(n0 + row0) * K + koff + k0 + sl0 * 8, (char*)Bls[buf] + idx0 * 16);
    stage16(A + (size_t)(m0 + row1) * K + koff + k0 + sl1 * 8, (char*)Als[buf] + idx1 * 16);
    stage16(Bt + (size_t)(n0 + row1) * K + koff + k0 + sl1 * 8, (char*)Bls[buf] + idx1 * 16);
  };

  stage(0, 0);
  __syncthreads();

  int nk = klen >> 5;
  for (int it = 0; it < nk; ++it) {
    int cur = it & 1;
    if (it + 1 < nk) stage((it + 1) << 5, cur ^ 1);
    bf16x8 af[4], bfr[4];
#pragma unroll
    for (int mi = 0; mi < 4; ++mi) {
      int r = wm * 64 + mi * 16 + lrow;
      int sl = g ^ ((r >> 1) & 3);
      af[mi] = *(const bf16x8*)((const char*)Als[cur] + r * 64 + sl * 16);
    }
#pragma unroll
    for (int ni = 0; ni < 4; ++ni) {
      int r = wn * 64 + ni * 16 + lrow;
      int sl = g ^ ((r >> 1) & 3);
      bfr[ni] = *(const bf16x8*)((const char*)Bls[cur] + r * 64 + sl * 16);
    }
    __builtin_amdgcn_s_setprio(1);
#pragma unroll
    for (int mi = 0; mi < 4; ++mi)
#pragma unroll
      for (int ni = 0; ni < 4; ++ni)
        acc[mi][ni] = mfma32(af[mi], bfr[ni], acc[mi][ni]);
    __builtin_amdgcn_s_setprio(0);
    __syncthreads();
  }

#pragma unroll
  for (int mi = 0; mi < 4; ++mi)
#pragma unroll
    for (int ni = 0; ni < 4; ++ni)
#pragma unroll
      for (int reg = 0; reg < 4; ++reg) {
        int gm = m0 + wm * 64 + mi * 16 + g * 4 + reg;   // C row = 4*(l>>4)+reg
        int gn = n0 + wn * 64 + ni * 16 + lrow;          // C col = l&15
        float v = acc[mi][ni][reg];
        if (MODE == 0) {
          int p = gn / 768, nn = gn - p * 768;
          const float* bb = (p == 0) ? b0 : (p == 1 ? b1p : b2p);
          v += bb[nn];
          int b = gm >> 11, s = gm & 2047;
          int h = nn >> 6, dh = nn & 63;
          size_t hh = (size_t)(b * 12 + h);
          // Q pre-scaled by 1/sqrt(64) * log2(e) so attention can use exp2
          if (p == 0)      outQ[(hh * 2048 + s) * 64 + dh] = f2bf(v * 0.1803368801f);
          else if (p == 1) outK[(hh * 2048 + s) * 64 + dh] = f2bf(v);
          else             outV[(hh * 64 + dh) * 2048 + s] = f2bf(v);
        } else if (MODE == 2) {
          if (bz == 1) {
            v += b0[gn] + bf2f(resid[(size_t)gm * 768 + gn]);
            outK[(size_t)gm * 768 + gn] = f2bf(v);
          } else {
            outQ[(size_t)gm * 768 + gn] = f2bf(v);
          }
        } else {                       // MODE 4: f32 transposed partial
          outP[(size_t)gn * 768 + gm] = v;
        }
      }
}

// plain GEMM kernel wrapper (used for FFN MODE 2)
template <int MODE, int OCC>
__global__ __launch_bounds__(256, OCC) void gemm_k(
    const u16* __restrict__ A, const u16* __restrict__ Bt, int K,
    const float* __restrict__ b0, const u16* __restrict__ resid,
    u16* __restrict__ out0, u16* __restrict__ out1) {
  __shared__ u16 Als[2][128 * 32];
  __shared__ u16 Bls[2][128 * 32];
  gemm_body<MODE>(Als, Bls, A, Bt, K, b0, nullptr, nullptr, resid,
                  out0, out1, nullptr, nullptr, blockIdx.x, blockIdx.y, blockIdx.z);
}

// fused dispatcher with 1:7 work:mask INTERLEAVE so the HBM-bound mask pack
// overlaps the latency-bound GEMM blocks instead of serializing at the tail.
// Work blocks (2064): W12 split-K/4 partials (144) + QKV (1152) + bias_eff (768).
// Mask blocks (16384): 4 waves x 4 u64 words each. OCC=4 (R17: OCC=5 spills).
__global__ __launch_bounds__(256, 4) void fused_gemms(
    const u16* __restrict__ Xb, const u16* __restrict__ WqkvT,
    const float* __restrict__ bq, const float* __restrict__ bk, const float* __restrict__ bv,
    u16* __restrict__ Qb, u16* __restrict__ Kb, u16* __restrict__ Vtb,
    const u16* __restrict__ W1b, const u16* __restrict__ W2T, float* __restrict__ W12P,
    const float* __restrict__ b1, const float* __restrict__ b2, float* __restrict__ biasEff,
    const int* __restrict__ maskI, unsigned long long* __restrict__ bits) {
  __shared__ u16 Als[2][128 * 32];
  __shared__ u16 Bls[2][128 * 32];
  const int bid = blockIdx.x;          // 0..18447
  const int q8 = bid >> 3;
  if ((bid & 7) == 0 && q8 < 2064) {   // work block wk = q8
    const int wk = q8;
    if (wk < 144) {                    // W12 partials: 4 z-slices x (6 x 6) tiles
      int z = wk / 36, tl = wk % 36;
      gemm_body<4>(Als, Bls, W1b, W2T, 3072, nullptr, nullptr, nullptr, nullptr,
                   nullptr, nullptr, nullptr, W12P + (size_t)z * 768 * 768,
                   tl % 6, tl / 6, z);
    } else if (wk < 1296) {            // QKV: dim (18, 64), x fast
      int lb = wk - 144;
      gemm_body<0>(Als, Bls, Xb, WqkvT, 768, bq, bk, bv, nullptr,
                   Qb, Kb, Vtb, nullptr, lb % 18, lb / 18, 0);
    } else {                           // bias_eff[j] = b2[j] + sum_k b1[k]*W2[k][j]
      const int j = wk - 1296, t = threadIdx.x;
      float* red = (float*)Als;        // reuse LDS
      float s = 0.f;
      for (int k = t; k < 3072; k += 256) s += b1[k] * bf2f(W2T[(size_t)j * 3072 + k]);
      for (int d = 1; d < 64; d <<= 1) s += __shfl_xor(s, d, 64);
      if ((t & 63) == 0) red[t >> 6] = s;
      __syncthreads();
      if (t == 0) biasEff[j] = b2[j] + red[0] + red[1] + red[2] + red[3];
    }
  } else {                             // mask block: bijective index
    const int nwork = (q8 < 2064) ? (q8 + 1) : 2064;
    const int mi = bid - nwork;        // 0..16383
    const int t = threadIdx.x;
    int lane = t & 63;
    int w0 = (mi * 4 + (t >> 6)) * 4;
#pragma unroll
    for (int j = 0; j < 4; ++j) {
      int v = maskI[(size_t)(w0 + j) * 64 + lane];
      unsigned long long bm = __ballot(v != 0);
      if (lane == 0) bits[w0 + j] = bm;
    }
  }
}

// ---------- fused masked flash attention (fixed-max softmax, swapped QK^T) ----------
// QBLK=128: 1D grid 768 (XCD-swizzled), 8 waves x 16 q-rows, KV tiles of 64.
// R18-proven config: the plateau structure (88-89us); LDS 48KB -> 3 blocks/CU.
__global__ __launch_bounds__(512, 6) void attn_fwd(
    const u16* __restrict__ Q, const u16* __restrict__ Kg, const u16* __restrict__ Vt,
    const unsigned long long* __restrict__ mbits, u16* __restrict__ attn_out) {
  __shared__ u16 Kls[2][64 * 64];   // 16KB
  __shared__ u16 Vls[2][64 * 64];   // 16KB
  __shared__ u16 Pls[8][16 * 64];   // 16KB: per-wave P[16q][64k]
  const int t = threadIdx.x, lane = t & 63, wv = t >> 6;
  const int lrow = lane & 15, g = lane >> 4;

  // XCD-aware swizzle: 768 % 8 == 0, bijective; each XCD gets 6 bh x 16 qtiles
  const int fid = blockIdx.x;
  const int swz = (fid & 7) * 96 + (fid >> 3);
  const int bh = swz >> 4, q0 = (swz & 15) * 128;
  const int b = bh / 12, h = bh % 12;
  const u16* Qh = Q + (size_t)bh * 2048 * 64;
  const u16* Kh = Kg + (size_t)bh * 2048 * 64;
  const u16* Vh = Vt + (size_t)bh * 64 * 2048;

  const int qr = q0 + wv * 16 + lrow;                 // this lane's q-row
  bf16x8 aq[2];
  aq[0] = *(const bf16x8*)(Qh + (size_t)qr * 64 + g * 8);
  aq[1] = *(const bf16x8*)(Qh + (size_t)qr * 64 + 32 + g * 8);

  bf16x8 ones;
#pragma unroll
  for (int j = 0; j < 8; ++j) ones[j] = (__bf16)1.0f;

  f32x4 acc[4] = {};
  f32x4 lacc = {};                                    // row-sum accumulator

  // staging: 512 threads cover K(64x64) and V(64x64), one 16B slot each
  const int row0 = t >> 3, sl0 = (t & 7) ^ (row0 & 7);
  auto stage = [&](int kt, int buf) {
    stage16(Kh + ((size_t)(kt * 64 + row0)) * 64 + sl0 * 8, (char*)Kls[buf] + t * 16);
    stage16(Vh + (size_t)row0 * 2048 + kt * 64 + sl0 * 8, (char*)Vls[buf] + t * 16);
  };

  const unsigned long long* mrow = mbits + ((size_t)b * 2048 + qr) * 32;
  unsigned long long mb = mrow[0];

  stage(0, 0);
  __syncthreads();

#pragma unroll 2
  for (int kt = 0; kt < 32; ++kt) {
    const int cur = kt & 1;
    if (kt + 1 < 32) stage(kt + 1, cur ^ 1);

    // S^T = K Q^T per wave: C col = q (lane-local), row = k_local = 4g+reg
    f32x4 sc[4];
#pragma unroll
    for (int c = 0; c < 4; ++c) {
      sc[c] = 0.f;
#pragma unroll
      for (int ks = 0; ks < 2; ++ks) {
        int r = c * 16 + lrow;
        int sl = (ks * 4 + g) ^ (r & 7);
        bf16x8 bk = *(const bf16x8*)((const char*)Kls[cur] + r * 128 + sl * 16);
        sc[c] = mfma32(bk, aq[ks], sc[c]);            // swapped operands
      }
    }

    unsigned long long mbn = (kt + 1 < 32) ? mrow[kt + 1] : 0;  // prefetch

    // fixed-max softmax; this lane's k values are k = 16c + 4g + reg
    unsigned mlo = (unsigned)mb, mhi = (unsigned)(mb >> 32);
#pragma unroll
    for (int c = 0; c < 4; ++c) {
      unsigned bits = ((c & 2) ? mhi : mlo) >> ((c & 1) * 16 + 4 * g);
#pragma unroll
      for (int reg = 0; reg < 4; ++reg)
        sc[c][reg] = ((bits >> reg) & 1) ? 0.f : __builtin_amdgcn_exp2f(sc[c][reg]);
    }
    mb = mbn;

    // P[q][k] -> per-wave swizzled LDS: 4x ds_write_b64, k-adjacent bf16 packs
#pragma unroll
    for (int c = 0; c < 4; ++c) {
      bf16x4 pk;
#pragma unroll
      for (int reg = 0; reg < 4; ++reg) pk[reg] = (__bf16)sc[c][reg];
      int slot = 2 * c + (g >> 1);                    // k = 16c + 4g .. +3
      int byte = lrow * 128 + ((slot ^ (lrow & 7)) << 4) + (g & 1) * 8;
      *(bf16x4*)((char*)Pls[wv] + byte) = pk;
    }
    asm volatile("s_waitcnt lgkmcnt(0)" ::: "memory");   // intra-wave cross-lane LDS vis

#pragma unroll
    for (int ks = 0; ks < 2; ++ks) {
      int slp = (ks * 4 + g) ^ (lrow & 7);
      bf16x8 pa = *(const bf16x8*)((const char*)Pls[wv] + lrow * 128 + slp * 16);
      lacc = mfma32(pa, ones, lacc);                   // denominator on matrix pipe
#pragma unroll
      for (int c = 0; c < 4; ++c) {
        int r = c * 16 + lrow;
        int sl = (ks * 4 + g) ^ (r & 7);
        bf16x8 vf = *(const bf16x8*)((const char*)Vls[cur] + r * 128 + sl * 16);
        acc[c] = mfma32(pa, vf, acc[c]);
      }
    }
    __syncthreads();
  }

  float rl[4];
#pragma unroll
  for (int reg = 0; reg < 4; ++reg) rl[reg] = 1.0f / lacc[reg];
#pragma unroll
  for (int c = 0; c < 4; ++c)
#pragma unroll
    for (int reg = 0; reg < 4; ++reg) {
      int q = q0 + wv * 16 + 4 * g + reg;
      int col = h * 64 + c * 16 + lrow;
      attn_out[((size_t)b * 2048 + q) * 768 + col] = f2bf(acc[c][reg] * rl[reg]);
    }
}

// ---------- fused add+LN (rows < nrows) + W12 reduce (extra blocks) ----------
__global__ __launch_bounds__(192) void ln_fused2(
    const u16* __restrict__ x1b, const u16* __restrict__ x2b,
    const float* __restrict__ gam, const float* __restrict__ bet,
    float* __restrict__ outf, u16* __restrict__ outb,
    const float* __restrict__ W12P, u16* __restrict__ W12T, int nrows) {
  const int row = blockIdx.x, t = threadIdx.x;
  __shared__ float red[3];
  if (row >= nrows) {                  // W12 partial reduce
    const int i = (row - nrows) * 192 + t;
    float4 s = ((const float4*)W12P)[i];
#pragma unroll
    for (int z = 1; z < 4; ++z) {
      float4 q = ((const float4*)(W12P + (size_t)z * 768 * 768))[i];
      s.x += q.x; s.y += q.y; s.z += q.z; s.w += q.w;
    }
    ushort4 u;
    u.x = f2bf(s.x); u.y = f2bf(s.y); u.z = f2bf(s.z); u.w = f2bf(s.w);
    ((ushort4*)W12T)[i] = u;
    return;
  }
  const size_t base = (size_t)row * 768 + t * 4;
  bf16x4 a = *(const bf16x4*)(x1b + base);
  bf16x4 c = *(const bf16x4*)(x2b + base);
  float v[4], s = 0.f;
#pragma unroll
  for (int j = 0; j < 4; ++j) { v[j] = (float)a[j] + (float)c[j]; s += v[j]; }
  for (int d = 1; d < 64; d <<= 1) s += __shfl_xor(s, d, 64);
  if ((t & 63) == 0) red[t >> 6] = s;
  __syncthreads();
  s = red[0] + red[1] + red[2];
  float mu = s * (1.f / 768.f);
  float sq = 0.f;
#pragma unroll
  for (int j = 0; j < 4; ++j) { float d = v[j] - mu; sq += d * d; }
  __syncthreads();
  for (int d = 1; d < 64; d <<= 1) sq += __shfl_xor(sq, d, 64);
  if ((t & 63) == 0) red[t >> 6] = sq;
  __syncthreads();
  sq = red[0] + red[1] + red[2];
  float rs = rsqrtf(sq * (1.f / 768.f) + 1e-5f);
  const int i0 = t * 4;
  float y[4];
#pragma unroll
  for (int j = 0; j < 4; ++j) y[j] = (v[j] - mu) * rs * gam[i0 + j] + bet[i0 + j];
  if (outf) {
    float4 o = make_float4(y[0], y[1], y[2], y[3]);
    *(float4*)(outf + base) = o;
  }
  if (outb) {
    ushort4 u;
    u.x = f2bf(y[0]); u.y = f2bf(y[1]); u.z = f2bf(y[2]); u.w = f2bf(y[3]);
    *(ushort4*)(outb + base) = u;
  }
}

// ---------- launch ----------
extern "C" void kernel_launch(void* const* d_in, const int* in_sizes, int n_in,
                              void* d_out, int out_size, void* d_ws, size_t ws_size,
                              hipStream_t stream) {
  const float* inputs = (const float*)d_in[0];
  const int*   maskI  = (const int*)d_in[1];
  const float* Wq = (const float*)d_in[2];  const float* bq = (const float*)d_in[3];
  const float* Wk = (const float*)d_in[4];  const float* bk = (const float*)d_in[5];
  const float* Wv = (const float*)d_in[6];  const float* bv = (const float*)d_in[7];
  const float* g1 = (const float*)d_in[8];  const float* be1 = (const float*)d_in[9];
  const float* W1 = (const float*)d_in[10]; const float* b1 = (const float*)d_in[11];
  const float* W2 = (const float*)d_in[12]; const float* b2 = (const float*)d_in[13];
  const float* g2 = (const float*)d_in[14]; const float* be2 = (const float*)d_in[15];
  float* out = (float*)d_out;

  char* w = (char*)d_ws;
  auto take = [&](size_t n) { char* p = w; w += (n + 255) & ~(size_t)255; return p; };
  u16* WqkvT = (u16*)take((size_t)2304 * 768 * 2);
  u16* W1b   = (u16*)take((size_t)768 * 3072 * 2);        // W1 bf16 row-major
  u16* W2T   = (u16*)take((size_t)768 * 3072 * 2);        // W2^T bf16
  u16* W12T  = (u16*)take((size_t)768 * 768 * 2);         // (W1@W2)^T bf16
  float* W12P = (float*)take((size_t)4 * 768 * 768 * 4);  // split-K f32 partials
  float* biasEff = (float*)take((size_t)768 * 4);
  u16* Xb    = (u16*)take((size_t)8192 * 768 * 2);
  u16* Qb    = (u16*)take((size_t)48 * 2048 * 64 * 2);    // dead after attn; pre0b overlays
  u16* Kb    = (u16*)take((size_t)48 * 2048 * 64 * 2);    // dead after attn; pre1b overlays
  u16* Vtb   = (u16*)take((size_t)48 * 64 * 2048 * 2);
  unsigned long long* mbits = (unsigned long long*)take((size_t)4 * 2048 * 32 * 8);
  u16*   attnB   = (u16*)take((size_t)8192 * 768 * 2);    // attn out, bf16
  u16*   ffnB    = (u16*)take((size_t)8192 * 768 * 2);    // LN1 out, bf16
  if ((size_t)(w - (char*)d_ws) > ws_size) return;
  u16* pre0b = Qb;            // FFN split-K partial z=0, bf16 (12.6MB each)
  u16* pre1b = Kb;            // FFN split-K partial z=1 (+bias+resid), bf16

  prep_all<<<12480, 256, 0, stream>>>(Wq, Wk, Wv, W1, W2, inputs,
                                      WqkvT, W1b, W2T, Xb);
  // interleaved: W12 partials + QKV + bias_eff (1-in-8 bids) | mask pack (7-in-8)
  fused_gemms<<<18448, 256, 0, stream>>>(Xb, WqkvT, bq, bk, bv, Qb, Kb, Vtb,
                                         W1b, W2T, W12P, b1, b2, biasEff,
                                         maskI, mbits);
  attn_fwd<<<768, 512, 0, stream>>>(Qb, Kb, Vtb, mbits, attnB);
  // LN1 (8192 rows) + W12 reduce (768 extra blocks)
  ln_fused2<<<8960, 192, 0, stream>>>(attnB, Xb, g1, be1, nullptr, ffnB,
                                      W12P, W12T, 8192);
  // collapsed FFN: out = ffnB @ W12 + biasEff + ffnB  (split-K=2, bf16 partials)
  gemm_k<2, 4><<<dim3(6, 64, 2), 256, 0, stream>>>(ffnB, W12T, 768, biasEff, ffnB,
                                                   pre0b, pre1b);
  ln_fused2<<<8192, 192, 0, stream>>>(pre0b, pre1b, g2, be2, out, nullptr,
                                      nullptr, nullptr, 8192);
}

// Round 23
// 232.601 us; speedup vs baseline: 2.3112x; 2.3112x over previous
//
#include <hip/hip_runtime.h>

typedef unsigned short u16;
typedef __attribute__((ext_vector_type(8))) __bf16 bf16x8;
typedef __attribute__((ext_vector_type(4))) __bf16 bf16x4;
typedef __attribute__((ext_vector_type(4))) float f32x4;

#define DEV __device__ __forceinline__

// ---------- helpers ----------
DEV u16 f2bf(float f) {                       // RNE float -> bf16 bits
  unsigned u = __builtin_bit_cast(unsigned, f);
  u += 0x7FFFu + ((u >> 16) & 1u);
  return (u16)(u >> 16);
}
DEV float bf2f(u16 u) {
  unsigned v = (unsigned)u << 16;
  return __builtin_bit_cast(float, v);
}

DEV void stage16(const void* g, void* l) {    // async global->LDS, 16B/lane
  __builtin_amdgcn_global_load_lds((const __attribute__((address_space(1))) void*)g,
                                   (__attribute__((address_space(3))) void*)l, 16, 0, 0);
}

DEV f32x4 mfma32(bf16x8 a, bf16x8 b, f32x4 c) {
  return __builtin_amdgcn_mfma_f32_16x16x32_bf16(a, b, c, 0, 0, 0);
}

// ---------- fused prep: weight transposes + W1 cast + input cast ----------
DEV void transpose_tile(const float* __restrict__ src, u16* __restrict__ dst,
                        int R, int C, int bx, int by, int t, float (*tile)[33]) {
  int tx = t & 31, ty = t >> 5;
  int c0 = bx * 32, r0 = by * 32;
#pragma unroll
  for (int i = 0; i < 4; ++i)
    tile[ty + i * 8][tx] = src[(size_t)(r0 + ty + i * 8) * C + c0 + tx];
  __syncthreads();
#pragma unroll
  for (int i = 0; i < 4; ++i)
    dst[(size_t)(c0 + ty + i * 8) * R + r0 + tx] = f2bf(tile[tx][ty + i * 8]);
}

__global__ __launch_bounds__(256) void prep_all(
    const float* __restrict__ Wq, const float* __restrict__ Wk, const float* __restrict__ Wv,
    const float* __restrict__ W1, const float* __restrict__ W2,
    const float* __restrict__ inputs,
    u16* __restrict__ WqkvT, u16* __restrict__ W1b, u16* __restrict__ W2T,
    u16* __restrict__ Xb) {
  __shared__ float tile[32][33];
  const int t = threadIdx.x;
  const int bid = blockIdx.x;
  if (bid < 1728) {                    // Wq/Wk/Wv: 3 x (24 x 24) tiles of 768x768
    int z = bid / 576, rem = bid % 576;
    const float* src = (z == 0) ? Wq : (z == 1 ? Wk : Wv);
    transpose_tile(src, WqkvT + (size_t)z * 768 * 768, 768, 768, rem % 24, rem / 24, t, tile);
  } else if (bid < 4032) {             // W2 [3072][768] -> W2T [768][3072]
    int rem = bid - 1728;
    transpose_tile(W2, W2T, 3072, 768, rem % 24, rem / 24, t, tile);
  } else if (bid < 6336) {             // cast W1 f32 -> bf16 row-major, 2304 blocks
    int i = (bid - 4032) * 256 + t;
    float4 f = ((const float4*)W1)[i];
    ushort4 u;
    u.x = f2bf(f.x); u.y = f2bf(f.y); u.z = f2bf(f.z); u.w = f2bf(f.w);
    ((ushort4*)W1b)[i] = u;
  } else {                             // cast inputs f32 -> bf16, 6144 blocks
    int i = (bid - 6336) * 256 + t;
    float4 f = ((const float4*)inputs)[i];
    ushort4 u;
    u.x = f2bf(f.x); u.y = f2bf(f.y); u.z = f2bf(f.z); u.w = f2bf(f.w);
    ((ushort4*)Xb)[i] = u;
  }
}

// ---------- bf16 GEMM body: C[M,N] = A[M,K] @ Bt[N,K]^T, 128x128 tile, BK=32 ----------
// MODE 0: QKV epilogue (scatter Q*scale,K to [bh,s,dh]; V to [bh,dh,s])
// MODE 2: split-K/2 by bz: z=0 raw partial bf16 -> outQ; z=1 partial+bias+resid bf16 -> outK
// MODE 4: split-K/4 by bz: f32 transposed partial -> outP (W12 = W1 @ W2)
template <int MODE>
DEV void gemm_body(u16 (*Als)[128 * 32], u16 (*Bls)[128 * 32],
                   const u16* __restrict__ A, const u16* __restrict__ Bt, int K,
                   const float* __restrict__ b0, const float* __restrict__ b1p,
                   const float* __restrict__ b2p, const u16* __restrict__ resid,
                   u16* __restrict__ outQ, u16* __restrict__ outK, u16* __restrict__ outV,
                   float* __restrict__ outP, int bx, int by, int bz) {
  const int t = threadIdx.x;
  const int lane = t & 63, wv = t >> 6;
  const int wm = wv & 1, wn = wv >> 1;
  const int lrow = lane & 15, g = lane >> 4;
  const int m0 = by * 128, n0 = bx * 128;

  int koff = 0, klen = K;
  if (MODE == 2) { klen = K >> 1; koff = bz * klen; }
  if (MODE == 4) { klen = K >> 2; koff = bz * klen; }

  f32x4 acc[4][4] = {};

  const int idx0 = t, idx1 = 256 + t;
  const int row0 = idx0 >> 2, sl0 = (idx0 & 3) ^ ((row0 >> 1) & 3);
  const int row1 = idx1 >> 2, sl1 = (idx1 & 3) ^ ((row1 >> 1) & 3);

  auto stage = [&](int k0, int buf) {
    stage16(A + (size_t)(m0 + row0) * K + koff + k0 + sl0 * 8, (char*)Als[buf] + idx0 * 16);
    stage16(Bt + (size_t)(n0 + row0) * K + koff + k0 + sl0 * 8, (char*)Bls[buf] + idx0 * 16);
    stage16(A + (size_t)(m0 + row1) * K + koff + k0 + sl1 * 8, (char*)Als[buf] + idx1 * 16);
    stage16(Bt + (size_t)(n0 + row1) * K + koff + k0 + sl1 * 8, (char*)Bls[buf] + idx1 * 16);
  };

  stage(0, 0);
  __syncthreads();

  int nk = klen >> 5;
  for (int it = 0; it < nk; ++it) {
    int cur = it & 1;
    if (it + 1 < nk) stage((it + 1) << 5, cur ^ 1);
    bf16x8 af[4], bfr[4];
#pragma unroll
    for (int mi = 0; mi < 4; ++mi) {
      int r = wm * 64 + mi * 16 + lrow;
      int sl = g ^ ((r >> 1) & 3);
      af[mi] = *(const bf16x8*)((const char*)Als[cur] + r * 64 + sl * 16);
    }
#pragma unroll
    for (int ni = 0; ni < 4; ++ni) {
      int r = wn * 64 + ni * 16 + lrow;
      int sl = g ^ ((r >> 1) & 3);
      bfr[ni] = *(const bf16x8*)((const char*)Bls[cur] + r * 64 + sl * 16);
    }
    __builtin_amdgcn_s_setprio(1);
#pragma unroll
    for (int mi = 0; mi < 4; ++mi)
#pragma unroll
      for (int ni = 0; ni < 4; ++ni)
        acc[mi][ni] = mfma32(af[mi], bfr[ni], acc[mi][ni]);
    __builtin_amdgcn_s_setprio(0);
    __syncthreads();
  }

#pragma unroll
  for (int mi = 0; mi < 4; ++mi)
#pragma unroll
    for (int ni = 0; ni < 4; ++ni)
#pragma unroll
      for (int reg = 0; reg < 4; ++reg) {
        int gm = m0 + wm * 64 + mi * 16 + g * 4 + reg;   // C row = 4*(l>>4)+reg
        int gn = n0 + wn * 64 + ni * 16 + lrow;          // C col = l&15
        float v = acc[mi][ni][reg];
        if (MODE == 0) {
          int p = gn / 768, nn = gn - p * 768;
          const float* bb = (p == 0) ? b0 : (p == 1 ? b1p : b2p);
          v += bb[nn];
          int b = gm >> 11, s = gm & 2047;
          int h = nn >> 6, dh = nn & 63;
          size_t hh = (size_t)(b * 12 + h);
          // Q pre-scaled by 1/sqrt(64) * log2(e) so attention can use exp2
          if (p == 0)      outQ[(hh * 2048 + s) * 64 + dh] = f2bf(v * 0.1803368801f);
          else if (p == 1) outK[(hh * 2048 + s) * 64 + dh] = f2bf(v);
          else             outV[(hh * 64 + dh) * 2048 + s] = f2bf(v);
        } else if (MODE == 2) {
          if (bz == 1) {
            v += b0[gn] + bf2f(resid[(size_t)gm * 768 + gn]);
            outK[(size_t)gm * 768 + gn] = f2bf(v);
          } else {
            outQ[(size_t)gm * 768 + gn] = f2bf(v);
          }
        } else {                       // MODE 4: f32 transposed partial
          outP[(size_t)gn * 768 + gm] = v;
        }
      }
}

// plain GEMM kernel wrapper (used for FFN MODE 2)
template <int MODE, int OCC>
__global__ __launch_bounds__(256, OCC) void gemm_k(
    const u16* __restrict__ A, const u16* __restrict__ Bt, int K,
    const float* __restrict__ b0, const u16* __restrict__ resid,
    u16* __restrict__ out0, u16* __restrict__ out1) {
  __shared__ u16 Als[2][128 * 32];
  __shared__ u16 Bls[2][128 * 32];
  gemm_body<MODE>(Als, Bls, A, Bt, K, b0, nullptr, nullptr, resid,
                  out0, out1, nullptr, nullptr, blockIdx.x, blockIdx.y, blockIdx.z);
}

// fused dispatcher: W12 split-K/4 partials (144, FIRST: hide under QKV) +
// QKV GEMM (1152) + bias_eff (768, hides in QKV drain) + mask pack (16384,
// appended tail — R22 proved interleaving poisons the dispatch pipeline).
// OCC=4 (R17: OCC=5 spills).
__global__ __launch_bounds__(256, 4) void fused_gemms(
    const u16* __restrict__ Xb, const u16* __restrict__ WqkvT,
    const float* __restrict__ bq, const float* __restrict__ bk, const float* __restrict__ bv,
    u16* __restrict__ Qb, u16* __restrict__ Kb, u16* __restrict__ Vtb,
    const u16* __restrict__ W1b, const u16* __restrict__ W2T, float* __restrict__ W12P,
    const float* __restrict__ b1, const float* __restrict__ b2, float* __restrict__ biasEff,
    const int* __restrict__ maskI, unsigned long long* __restrict__ bits) {
  __shared__ u16 Als[2][128 * 32];
  __shared__ u16 Bls[2][128 * 32];
  const int bid = blockIdx.x;
  if (bid < 144) {                     // W12 partials: 4 z-slices x (6 x 6) tiles
    int z = bid / 36, tl = bid % 36;
    gemm_body<4>(Als, Bls, W1b, W2T, 3072, nullptr, nullptr, nullptr, nullptr,
                 nullptr, nullptr, nullptr, W12P + (size_t)z * 768 * 768,
                 tl % 6, tl / 6, z);
  } else if (bid < 1296) {             // QKV: dim (18, 64), x fast
    int lb = bid - 144;
    gemm_body<0>(Als, Bls, Xb, WqkvT, 768, bq, bk, bv, nullptr,
                 Qb, Kb, Vtb, nullptr, lb % 18, lb / 18, 0);
  } else if (bid < 2064) {             // bias_eff[j] = b2[j] + sum_k b1[k]*W2[k][j]
    const int j = bid - 1296, t = threadIdx.x;
    float* red = (float*)Als;          // reuse LDS
    float s = 0.f;
    for (int k = t; k < 3072; k += 256) s += b1[k] * bf2f(W2T[(size_t)j * 3072 + k]);
    for (int d = 1; d < 64; d <<= 1) s += __shfl_xor(s, d, 64);
    if ((t & 63) == 0) red[t >> 6] = s;
    __syncthreads();
    if (t == 0) biasEff[j] = b2[j] + red[0] + red[1] + red[2] + red[3];
  } else {                             // pack mask bits: 16384 blocks x 16 words
    const int lb = bid - 2064, t = threadIdx.x;
    int lane = t & 63;
    int w0 = (lb * 4 + (t >> 6)) * 4;
#pragma unroll
    for (int j = 0; j < 4; ++j) {
      int v = maskI[(size_t)(w0 + j) * 64 + lane];
      unsigned long long bm = __ballot(v != 0);
      if (lane == 0) bits[w0 + j] = bm;
    }
  }
}

// ---------- fused masked flash attention (fixed-max softmax, swapped QK^T) ----------
// QBLK=128: 1D grid 768 (XCD-swizzled), 8 waves x 16 q-rows, KV tiles of 64.
// R18-proven config: the plateau structure (88-89us); LDS 48KB -> 3 blocks/CU.
__global__ __launch_bounds__(512, 6) void attn_fwd(
    const u16* __restrict__ Q, const u16* __restrict__ Kg, const u16* __restrict__ Vt,
    const unsigned long long* __restrict__ mbits, u16* __restrict__ attn_out) {
  __shared__ u16 Kls[2][64 * 64];   // 16KB
  __shared__ u16 Vls[2][64 * 64];   // 16KB
  __shared__ u16 Pls[8][16 * 64];   // 16KB: per-wave P[16q][64k]
  const int t = threadIdx.x, lane = t & 63, wv = t >> 6;
  const int lrow = lane & 15, g = lane >> 4;

  // XCD-aware swizzle: 768 % 8 == 0, bijective; each XCD gets 6 bh x 16 qtiles
  const int fid = blockIdx.x;
  const int swz = (fid & 7) * 96 + (fid >> 3);
  const int bh = swz >> 4, q0 = (swz & 15) * 128;
  const int b = bh / 12, h = bh % 12;
  const u16* Qh = Q + (size_t)bh * 2048 * 64;
  const u16* Kh = Kg + (size_t)bh * 2048 * 64;
  const u16* Vh = Vt + (size_t)bh * 64 * 2048;

  const int qr = q0 + wv * 16 + lrow;                 // this lane's q-row
  bf16x8 aq[2];
  aq[0] = *(const bf16x8*)(Qh + (size_t)qr * 64 + g * 8);
  aq[1] = *(const bf16x8*)(Qh + (size_t)qr * 64 + 32 + g * 8);

  bf16x8 ones;
#pragma unroll
  for (int j = 0; j < 8; ++j) ones[j] = (__bf16)1.0f;

  f32x4 acc[4] = {};
  f32x4 lacc = {};                                    // row-sum accumulator

  // staging: 512 threads cover K(64x64) and V(64x64), one 16B slot each
  const int row0 = t >> 3, sl0 = (t & 7) ^ (row0 & 7);
  auto stage = [&](int kt, int buf) {
    stage16(Kh + ((size_t)(kt * 64 + row0)) * 64 + sl0 * 8, (char*)Kls[buf] + t * 16);
    stage16(Vh + (size_t)row0 * 2048 + kt * 64 + sl0 * 8, (char*)Vls[buf] + t * 16);
  };

  const unsigned long long* mrow = mbits + ((size_t)b * 2048 + qr) * 32;
  unsigned long long mb = mrow[0];

  stage(0, 0);
  __syncthreads();

#pragma unroll 2
  for (int kt = 0; kt < 32; ++kt) {
    const int cur = kt & 1;
    if (kt + 1 < 32) stage(kt + 1, cur ^ 1);

    // S^T = K Q^T per wave: C col = q (lane-local), row = k_local = 4g+reg
    f32x4 sc[4];
#pragma unroll
    for (int c = 0; c < 4; ++c) {
      sc[c] = 0.f;
#pragma unroll
      for (int ks = 0; ks < 2; ++ks) {
        int r = c * 16 + lrow;
        int sl = (ks * 4 + g) ^ (r & 7);
        bf16x8 bk = *(const bf16x8*)((const char*)Kls[cur] + r * 128 + sl * 16);
        sc[c] = mfma32(bk, aq[ks], sc[c]);            // swapped operands
      }
    }

    unsigned long long mbn = (kt + 1 < 32) ? mrow[kt + 1] : 0;  // prefetch

    // fixed-max softmax; this lane's k values are k = 16c + 4g + reg
    unsigned mlo = (unsigned)mb, mhi = (unsigned)(mb >> 32);
#pragma unroll
    for (int c = 0; c < 4; ++c) {
      unsigned bits = ((c & 2) ? mhi : mlo) >> ((c & 1) * 16 + 4 * g);
#pragma unroll
      for (int reg = 0; reg < 4; ++reg)
        sc[c][reg] = ((bits >> reg) & 1) ? 0.f : __builtin_amdgcn_exp2f(sc[c][reg]);
    }
    mb = mbn;

    // P[q][k] -> per-wave swizzled LDS: 4x ds_write_b64, k-adjacent bf16 packs
#pragma unroll
    for (int c = 0; c < 4; ++c) {
      bf16x4 pk;
#pragma unroll
      for (int reg = 0; reg < 4; ++reg) pk[reg] = (__bf16)sc[c][reg];
      int slot = 2 * c + (g >> 1);                    // k = 16c + 4g .. +3
      int byte = lrow * 128 + ((slot ^ (lrow & 7)) << 4) + (g & 1) * 8;
      *(bf16x4*)((char*)Pls[wv] + byte) = pk;
    }
    asm volatile("s_waitcnt lgkmcnt(0)" ::: "memory");   // intra-wave cross-lane LDS vis

#pragma unroll
    for (int ks = 0; ks < 2; ++ks) {
      int slp = (ks * 4 + g) ^ (lrow & 7);
      bf16x8 pa = *(const bf16x8*)((const char*)Pls[wv] + lrow * 128 + slp * 16);
      lacc = mfma32(pa, ones, lacc);                   // denominator on matrix pipe
#pragma unroll
      for (int c = 0; c < 4; ++c) {
        int r = c * 16 + lrow;
        int sl = (ks * 4 + g) ^ (r & 7);
        bf16x8 vf = *(const bf16x8*)((const char*)Vls[cur] + r * 128 + sl * 16);
        acc[c] = mfma32(pa, vf, acc[c]);
      }
    }
    __syncthreads();
  }

  float rl[4];
#pragma unroll
  for (int reg = 0; reg < 4; ++reg) rl[reg] = 1.0f / lacc[reg];
#pragma unroll
  for (int c = 0; c < 4; ++c)
#pragma unroll
    for (int reg = 0; reg < 4; ++reg) {
      int q = q0 + wv * 16 + 4 * g + reg;
      int col = h * 64 + c * 16 + lrow;
      attn_out[((size_t)b * 2048 + q) * 768 + col] = f2bf(acc[c][reg] * rl[reg]);
    }
}

// ---------- fused add+LN (rows < nrows) + W12 reduce (extra blocks) ----------
__global__ __launch_bounds__(192) void ln_fused2(
    const u16* __restrict__ x1b, const u16* __restrict__ x2b,
    const float* __restrict__ gam, const float* __restrict__ bet,
    float* __restrict__ outf, u16* __restrict__ outb,
    const float* __restrict__ W12P, u16* __restrict__ W12T, int nrows) {
  const int row = blockIdx.x, t = threadIdx.x;
  __shared__ float red[3];
  if (row >= nrows) {                  // W12 partial reduce
    const int i = (row - nrows) * 192 + t;
    float4 s = ((const float4*)W12P)[i];
#pragma unroll
    for (int z = 1; z < 4; ++z) {
      float4 q = ((const float4*)(W12P + (size_t)z * 768 * 768))[i];
      s.x += q.x; s.y += q.y; s.z += q.z; s.w += q.w;
    }
    ushort4 u;
    u.x = f2bf(s.x); u.y = f2bf(s.y); u.z = f2bf(s.z); u.w = f2bf(s.w);
    ((ushort4*)W12T)[i] = u;
    return;
  }
  const size_t base = (size_t)row * 768 + t * 4;
  bf16x4 a = *(const bf16x4*)(x1b + base);
  bf16x4 c = *(const bf16x4*)(x2b + base);
  float v[4], s = 0.f;
#pragma unroll
  for (int j = 0; j < 4; ++j) { v[j] = (float)a[j] + (float)c[j]; s += v[j]; }
  for (int d = 1; d < 64; d <<= 1) s += __shfl_xor(s, d, 64);
  if ((t & 63) == 0) red[t >> 6] = s;
  __syncthreads();
  s = red[0] + red[1] + red[2];
  float mu = s * (1.f / 768.f);
  float sq = 0.f;
#pragma unroll
  for (int j = 0; j < 4; ++j) { float d = v[j] - mu; sq += d * d; }
  __syncthreads();
  for (int d = 1; d < 64; d <<= 1) sq += __shfl_xor(sq, d, 64);
  if ((t & 63) == 0) red[t >> 6] = sq;
  __syncthreads();
  sq = red[0] + red[1] + red[2];
  float rs = rsqrtf(sq * (1.f / 768.f) + 1e-5f);
  const int i0 = t * 4;
  float y[4];
#pragma unroll
  for (int j = 0; j < 4; ++j) y[j] = (v[j] - mu) * rs * gam[i0 + j] + bet[i0 + j];
  if (outf) {
    float4 o = make_float4(y[0], y[1], y[2], y[3]);
    *(float4*)(outf + base) = o;
  }
  if (outb) {
    ushort4 u;
    u.x = f2bf(y[0]); u.y = f2bf(y[1]); u.z = f2bf(y[2]); u.w = f2bf(y[3]);
    *(ushort4*)(outb + base) = u;
  }
}

// ---------- launch ----------
extern "C" void kernel_launch(void* const* d_in, const int* in_sizes, int n_in,
                              void* d_out, int out_size, void* d_ws, size_t ws_size,
                              hipStream_t stream) {
  const float* inputs = (const float*)d_in[0];
  const int*   maskI  = (const int*)d_in[1];
  const float* Wq = (const float*)d_in[2];  const float* bq = (const float*)d_in[3];
  const float* Wk = (const float*)d_in[4];  const float* bk = (const float*)d_in[5];
  const float* Wv = (const float*)d_in[6];  const float* bv = (const float*)d_in[7];
  const float* g1 = (const float*)d_in[8];  const float* be1 = (const float*)d_in[9];
  const float* W1 = (const float*)d_in[10]; const float* b1 = (const float*)d_in[11];
  const float* W2 = (const float*)d_in[12]; const float* b2 = (const float*)d_in[13];
  const float* g2 = (const float*)d_in[14]; const float* be2 = (const float*)d_in[15];
  float* out = (float*)d_out;

  char* w = (char*)d_ws;
  auto take = [&](size_t n) { char* p = w; w += (n + 255) & ~(size_t)255; return p; };
  u16* WqkvT = (u16*)take((size_t)2304 * 768 * 2);
  u16* W1b   = (u16*)take((size_t)768 * 3072 * 2);        // W1 bf16 row-major
  u16* W2T   = (u16*)take((size_t)768 * 3072 * 2);        // W2^T bf16
  u16* W12T  = (u16*)take((size_t)768 * 768 * 2);         // (W1@W2)^T bf16
  float* W12P = (float*)take((size_t)4 * 768 * 768 * 4);  // split-K f32 partials
  float* biasEff = (float*)take((size_t)768 * 4);
  u16* Xb    = (u16*)take((size_t)8192 * 768 * 2);
  u16* Qb    = (u16*)take((size_t)48 * 2048 * 64 * 2);    // dead after attn; pre0b overlays
  u16* Kb    = (u16*)take((size_t)48 * 2048 * 64 * 2);    // dead after attn; pre1b overlays
  u16* Vtb   = (u16*)take((size_t)48 * 64 * 2048 * 2);
  unsigned long long* mbits = (unsigned long long*)take((size_t)4 * 2048 * 32 * 8);
  u16*   attnB   = (u16*)take((size_t)8192 * 768 * 2);    // attn out, bf16
  u16*   ffnB    = (u16*)take((size_t)8192 * 768 * 2);    // LN1 out, bf16
  if ((size_t)(w - (char*)d_ws) > ws_size) return;
  u16* pre0b = Qb;            // FFN split-K partial z=0, bf16 (12.6MB each)
  u16* pre1b = Kb;            // FFN split-K partial z=1 (+bias+resid), bf16

  prep_all<<<12480, 256, 0, stream>>>(Wq, Wk, Wv, W1, W2, inputs,
                                      WqkvT, W1b, W2T, Xb);
  // W12 partials + QKV GEMM + bias_eff (hides in drain) + mask pack (appended tail)
  fused_gemms<<<18448, 256, 0, stream>>>(Xb, WqkvT, bq, bk, bv, Qb, Kb, Vtb,
                                         W1b, W2T, W12P, b1, b2, biasEff,
                                         maskI, mbits);
  attn_fwd<<<768, 512, 0, stream>>>(Qb, Kb, Vtb, mbits, attnB);
  // LN1 (8192 rows) + W12 reduce (768 extra blocks)
  ln_fused2<<<8960, 192, 0, stream>>>(attnB, Xb, g1, be1, nullptr, ffnB,
                                      W12P, W12T, 8192);
  // collapsed FFN: out = ffnB @ W12 + biasEff + ffnB  (split-K=2, bf16 partials)
  gemm_k<2, 4><<<dim3(6, 64, 2), 256, 0, stream>>>(ffnB, W12T, 768, biasEff, ffnB,
                                                   pre0b, pre1b);
  ln_fused2<<<8192, 192, 0, stream>>>(pre0b, pre1b, g2, be2, out, nullptr,
                                      nullptr, nullptr, 8192);
}